// Round 1
// baseline (115.340 us; speedup 1.0000x reference)
//
#include <hip/hip_runtime.h>

typedef float  f32x4  __attribute__((ext_vector_type(4)));
typedef short  short8 __attribute__((ext_vector_type(8)));
typedef short  short4_ __attribute__((ext_vector_type(4)));

constexpr int Bb = 8, T = 2048, D = 768, HS = 64;
constexpr int BT = Bb * T;

__device__ __forceinline__ short f2bf(float f) {
    unsigned u = __builtin_bit_cast(unsigned, f);
    unsigned r = (u + 0x7FFFu + ((u >> 16) & 1u)) >> 16;
    return (short)r;
}

// ---------------------------------------------------------------------------
// Kernel 0: transpose Wq|Wk|Wv (fp32 [768][64] each) -> Wt bf16 [192][768]
// so projection B-fragments are contiguous 16B loads.
// ---------------------------------------------------------------------------
__global__ __launch_bounds__(256) void wt_kernel(const float* __restrict__ Wq,
                                                 const float* __restrict__ Wk,
                                                 const float* __restrict__ Wv,
                                                 short* __restrict__ Wt) {
    int n = blockIdx.x;                       // 0..191 composite output col
    const float* W = (n < 64) ? Wq : (n < 128) ? Wk : Wv;
    int c = n & 63;
    for (int kk = threadIdx.x; kk < D; kk += 256)
        Wt[n * D + kk] = f2bf(W[kk * HS + c]);
}

// ---------------------------------------------------------------------------
// Kernel 1: QKV projection. 256 blocks x 64 rows. bf16 MFMA 16x16x32.
// q is pre-scaled by 1/8 (= HS^-0.5, exact exponent shift in bf16).
// ---------------------------------------------------------------------------
__global__ __launch_bounds__(256) void qkv_proj(const float* __restrict__ x,
                                                const short* __restrict__ Wt,
                                                short* __restrict__ qws,
                                                short* __restrict__ kws,
                                                short* __restrict__ vws) {
    __shared__ short xs[64][72];      // x tile, bf16, +8 pad (2-way max)
    __shared__ short wtile[192][72];  // Wt chunk, bf16

    const int tid  = threadIdx.x;
    const int lane = tid & 63, w = tid >> 6;
    const int lo   = lane & 15, hi = lane >> 4;
    const int row0 = blockIdx.x * 64;
    const int sr   = tid >> 2, sq = tid & 3;   // staging row / quarter

    f32x4 acc[12];
#pragma unroll
    for (int i = 0; i < 12; i++) acc[i] = f32x4{0.f, 0.f, 0.f, 0.f};

    for (int kc = 0; kc < 12; kc++) {
        // stage x chunk (64 rows x 64 k) fp32 -> bf16 LDS
#pragma unroll
        for (int i = 0; i < 4; i++) {
            float4 f = *reinterpret_cast<const float4*>(
                &x[(size_t)(row0 + sr) * D + kc * 64 + sq * 16 + i * 4]);
            short4_ h;
            h[0] = f2bf(f.x); h[1] = f2bf(f.y); h[2] = f2bf(f.z); h[3] = f2bf(f.w);
            *reinterpret_cast<short4_*>(&xs[sr][sq * 16 + i * 4]) = h;
        }
        // stage Wt chunk (192 cols x 64 k), already bf16
#pragma unroll
        for (int i = 0; i < 6; i++) {
            int sIdx = i * 256 + tid;           // 0..1535 segments of 8 elems
            int n = sIdx >> 3, off = (sIdx & 7) * 8;
            short8 v = *reinterpret_cast<const short8*>(&Wt[n * D + kc * 64 + off]);
            *reinterpret_cast<short8*>(&wtile[n][off]) = v;
        }
        __syncthreads();

        short8 a0 = *reinterpret_cast<const short8*>(&xs[w * 16 + lo][hi * 8]);
        short8 a1 = *reinterpret_cast<const short8*>(&xs[w * 16 + lo][32 + hi * 8]);
#pragma unroll
        for (int nt = 0; nt < 12; nt++) {
            short8 b0 = *reinterpret_cast<const short8*>(&wtile[nt * 16 + lo][hi * 8]);
            short8 b1 = *reinterpret_cast<const short8*>(&wtile[nt * 16 + lo][32 + hi * 8]);
            acc[nt] = __builtin_amdgcn_mfma_f32_16x16x32_bf16(a0, b0, acc[nt], 0, 0, 0);
            acc[nt] = __builtin_amdgcn_mfma_f32_16x16x32_bf16(a1, b1, acc[nt], 0, 0, 0);
        }
        __syncthreads();
    }

    // epilogue: acc -> bf16 q|k|v
#pragma unroll
    for (int nt = 0; nt < 12; nt++) {
        short* dst = (nt < 4) ? qws : (nt < 8) ? kws : vws;
        const float s = (nt < 4) ? 0.125f : 1.0f;
        const int c = (nt & 3) * 16 + lo;
#pragma unroll
        for (int r = 0; r < 4; r++) {
            int row = row0 + w * 16 + hi * 4 + r;
            dst[(size_t)row * HS + c] = f2bf(acc[nt][r] * s);
        }
    }
}

// ---------------------------------------------------------------------------
// Kernel 2: causal flash attention. 1 block per (batch, 64-row q tile).
// 4 waves x 16 q-rows. K/V tiles of 64 keys staged in LDS (V transposed).
// ---------------------------------------------------------------------------
__global__ __launch_bounds__(256) void attn(const short* __restrict__ qg,
                                            const short* __restrict__ kg,
                                            const short* __restrict__ vg,
                                            float* __restrict__ out) {
    __shared__ short ks[64][72];      // K tile  [key][hs]
    __shared__ short vt[64][72];      // V tile transposed [hs][key]
    __shared__ short ps[4][16][72];   // per-wave P tile [qrow][key]

    const int tid  = threadIdx.x;
    const int lane = tid & 63, w = tid >> 6;
    const int lo   = lane & 15, hi = lane >> 4;
    const int b    = blockIdx.x >> 5;         // T/64 = 32 q tiles
    const int qt   = blockIdx.x & 31;
    const size_t base = (size_t)b * T * HS;
    const int sr = tid >> 2, sg = tid & 3;

    // Q A-fragments in registers (row = lo, k-range by hi)
    const int qrow = qt * 64 + w * 16 + lo;
    short8 qa0 = *reinterpret_cast<const short8*>(&qg[base + (size_t)qrow * HS + hi * 8]);
    short8 qa1 = *reinterpret_cast<const short8*>(&qg[base + (size_t)qrow * HS + 32 + hi * 8]);

    float m_[4], l_[4];
    f32x4 oacc[4];
#pragma unroll
    for (int r = 0; r < 4; r++) { m_[r] = -1e30f; l_[r] = 0.0f; }
#pragma unroll
    for (int i = 0; i < 4; i++) oacc[i] = f32x4{0.f, 0.f, 0.f, 0.f};

    for (int kt = 0; kt <= qt; kt++) {
        // ---- stage K (row-major) and V (transposed) ----
        size_t krow = base + (size_t)(kt * 64 + sr) * HS;
        short8 k0 = *reinterpret_cast<const short8*>(&kg[krow + sg * 16]);
        short8 k1 = *reinterpret_cast<const short8*>(&kg[krow + sg * 16 + 8]);
        *reinterpret_cast<short8*>(&ks[sr][sg * 16])     = k0;
        *reinterpret_cast<short8*>(&ks[sr][sg * 16 + 8]) = k1;
        short8 v0 = *reinterpret_cast<const short8*>(&vg[krow + sg * 16]);
        short8 v1 = *reinterpret_cast<const short8*>(&vg[krow + sg * 16 + 8]);
#pragma unroll
        for (int e = 0; e < 8; e++) vt[sg * 16 + e][sr] = v0[e];
#pragma unroll
        for (int e = 0; e < 8; e++) vt[sg * 16 + 8 + e][sr] = v1[e];
        __syncthreads();

        // ---- S = Q K^T  (16 q-rows x 64 keys per wave) ----
        f32x4 sacc[4];
#pragma unroll
        for (int nt = 0; nt < 4; nt++) sacc[nt] = f32x4{0.f, 0.f, 0.f, 0.f};
#pragma unroll
        for (int nt = 0; nt < 4; nt++) {
            short8 b0 = *reinterpret_cast<const short8*>(&ks[nt * 16 + lo][hi * 8]);
            short8 b1 = *reinterpret_cast<const short8*>(&ks[nt * 16 + lo][32 + hi * 8]);
            sacc[nt] = __builtin_amdgcn_mfma_f32_16x16x32_bf16(qa0, b0, sacc[nt], 0, 0, 0);
            sacc[nt] = __builtin_amdgcn_mfma_f32_16x16x32_bf16(qa1, b1, sacc[nt], 0, 0, 0);
        }

        // ---- causal mask on the diagonal tile ----
        if (kt == qt) {
#pragma unroll
            for (int nt = 0; nt < 4; nt++)
#pragma unroll
                for (int r = 0; r < 4; r++)
                    if (nt * 16 + lo > w * 16 + hi * 4 + r) sacc[nt][r] = -1e30f;
        }

        // ---- online softmax (rows replicated across each 16-lane group) ----
#pragma unroll
        for (int r = 0; r < 4; r++) {
            float t0 = fmaxf(fmaxf(sacc[0][r], sacc[1][r]),
                             fmaxf(sacc[2][r], sacc[3][r]));
#pragma unroll
            for (int off = 1; off < 16; off <<= 1) t0 = fmaxf(t0, __shfl_xor(t0, off));
            float mnew = fmaxf(m_[r], t0);
            float corr = __expf(m_[r] - mnew);
            float psum = 0.0f;
#pragma unroll
            for (int nt = 0; nt < 4; nt++) {
                float p = __expf(sacc[nt][r] - mnew);
                sacc[nt][r] = p;
                psum += p;
            }
#pragma unroll
            for (int off = 1; off < 16; off <<= 1) psum += __shfl_xor(psum, off);
            l_[r] = l_[r] * corr + psum;
            m_[r] = mnew;
#pragma unroll
            for (int nt = 0; nt < 4; nt++) oacc[nt][r] *= corr;
        }

        // ---- P -> LDS bf16 (wave-private, no barrier needed) ----
#pragma unroll
        for (int nt = 0; nt < 4; nt++)
#pragma unroll
            for (int r = 0; r < 4; r++)
                ps[w][hi * 4 + r][nt * 16 + lo] = f2bf(sacc[nt][r]);

        // ---- O += P V ----
        short8 pa0 = *reinterpret_cast<const short8*>(&ps[w][lo][hi * 8]);
        short8 pa1 = *reinterpret_cast<const short8*>(&ps[w][lo][32 + hi * 8]);
#pragma unroll
        for (int nt = 0; nt < 4; nt++) {
            short8 b0 = *reinterpret_cast<const short8*>(&vt[nt * 16 + lo][hi * 8]);
            short8 b1 = *reinterpret_cast<const short8*>(&vt[nt * 16 + lo][32 + hi * 8]);
            oacc[nt] = __builtin_amdgcn_mfma_f32_16x16x32_bf16(pa0, b0, oacc[nt], 0, 0, 0);
            oacc[nt] = __builtin_amdgcn_mfma_f32_16x16x32_bf16(pa1, b1, oacc[nt], 0, 0, 0);
        }
        __syncthreads();
    }

    // ---- epilogue: divide by running denom, write fp32 ----
#pragma unroll
    for (int r = 0; r < 4; r++) {
        float inv = 1.0f / l_[r];
        int row = qt * 64 + w * 16 + hi * 4 + r;
#pragma unroll
        for (int nt = 0; nt < 4; nt++)
            out[base + (size_t)row * HS + nt * 16 + lo] = oacc[nt][r] * inv;
    }
}

// ---------------------------------------------------------------------------
extern "C" void kernel_launch(void* const* d_in, const int* in_sizes, int n_in,
                              void* d_out, int out_size, void* d_ws, size_t ws_size,
                              hipStream_t stream) {
    const float* x  = (const float*)d_in[0];
    const float* Wq = (const float*)d_in[1];
    const float* Wk = (const float*)d_in[2];
    const float* Wv = (const float*)d_in[3];
    float* out = (float*)d_out;

    short* ws  = (short*)d_ws;
    short* qws = ws;
    short* kws = ws + (size_t)BT * HS;
    short* vws = ws + (size_t)2 * BT * HS;
    short* Wt  = ws + (size_t)3 * BT * HS;   // [192][768] bf16

    wt_kernel<<<192, 256, 0, stream>>>(Wq, Wk, Wv, Wt);
    qkv_proj<<<BT / 64, 256, 0, stream>>>(x, Wt, qws, kws, vws);
    attn<<<Bb * (T / 64), 256, 0, stream>>>(qws, kws, vws, out);
}

// Round 2
// 90.093 us; speedup vs baseline: 1.2802x; 1.2802x over previous
//
#include <hip/hip_runtime.h>

typedef float  f32x4  __attribute__((ext_vector_type(4)));
typedef short  short8 __attribute__((ext_vector_type(8)));

constexpr int Bb = 8, T = 2048, D = 768, HS = 64;
constexpr int BT = Bb * T;
constexpr int QT = T / 64;              // 32 q-tiles per batch
constexpr int SPLIT = 2;
constexpr int PSTRIDE = 64 * 64 + 128;  // floats per partial (O' + m + l)

__device__ __forceinline__ short f2bf(float f) {
    unsigned u = __builtin_bit_cast(unsigned, f);
    unsigned r = (u + 0x7FFFu + ((u >> 16) & 1u)) >> 16;
    return (short)r;
}

// ---------------------------------------------------------------------------
// Kernel 0: transpose Wq|Wk|Wv (fp32 [768][64] each) -> Wt bf16 [192][768]
// ---------------------------------------------------------------------------
__global__ __launch_bounds__(256) void wt_kernel(const float* __restrict__ Wq,
                                                 const float* __restrict__ Wk,
                                                 const float* __restrict__ Wv,
                                                 short* __restrict__ Wt) {
    int n = blockIdx.x;                       // 0..191 composite output col
    const float* W = (n < 64) ? Wq : (n < 128) ? Wk : Wv;
    int c = n & 63;
    for (int kk = threadIdx.x; kk < D; kk += 256)
        Wt[n * D + kk] = f2bf(W[kk * HS + c]);
}

// ---------------------------------------------------------------------------
// Kernel 1: QKV projection. 512 blocks x 32 rows, 4 waves.
// x staged once in swizzled LDS; W read from L2 with imm-offset short8 loads.
// Writes q (pre-scaled 1/8) and k row-major bf16; v transposed [b][h][t].
// ---------------------------------------------------------------------------
__global__ __launch_bounds__(256) void qkv_proj(const float* __restrict__ x,
                                                const short* __restrict__ Wt,
                                                short* __restrict__ qws,
                                                short* __restrict__ kws,
                                                short* __restrict__ vtg) {
    __shared__ short xs[32 * 768];            // 48 KB, XOR-swizzled 16B segs

    const int tid  = threadIdx.x;
    const int lane = tid & 63, w = tid >> 6;
    const int lo   = lane & 15, hi = lane >> 4;
    const int row0 = blockIdx.x * 32;         // absolute row in BT
    const int b    = row0 >> 11;
    const int t0   = row0 & 2047;

    // ---- stage x (fp32 -> bf16), swizzled ----
    {
        const int r = tid >> 3, sg = tid & 7;
        const float* xp = &x[(size_t)(row0 + r) * D + sg * 96];
        const int r7 = r & 7;
#pragma unroll
        for (int i = 0; i < 12; i++) {
            float4 f0 = *reinterpret_cast<const float4*>(xp + i * 8);
            float4 f1 = *reinterpret_cast<const float4*>(xp + i * 8 + 4);
            short8 h;
            h[0] = f2bf(f0.x); h[1] = f2bf(f0.y); h[2] = f2bf(f0.z); h[3] = f2bf(f0.w);
            h[4] = f2bf(f1.x); h[5] = f2bf(f1.y); h[6] = f2bf(f1.z); h[7] = f2bf(f1.w);
            int seg = sg * 12 + i;
            *reinterpret_cast<short8*>(&xs[r * 768 + ((seg ^ r7) << 3)]) = h;
        }
    }
    __syncthreads();

    const int rt = w & 1, nh = w >> 1;        // row-tile, n-half
    f32x4 acc[6];
#pragma unroll
    for (int j = 0; j < 6; j++) acc[j] = f32x4{0.f, 0.f, 0.f, 0.f};

    const int arow = (rt * 16 + lo) * 768;
    const int l7 = lo & 7;
    const short* bbase[6];
#pragma unroll
    for (int j = 0; j < 6; j++)
        bbase[j] = &Wt[(size_t)((nh * 6 + j) * 16 + lo) * D + hi * 8];

    for (int kk = 0; kk < 24; kk++) {
        short8 a = *reinterpret_cast<const short8*>(
            &xs[arow + (((kk * 4 + hi) ^ l7) << 3)]);
#pragma unroll
        for (int j = 0; j < 6; j++) {
            short8 bv = *reinterpret_cast<const short8*>(bbase[j] + kk * 32);
            acc[j] = __builtin_amdgcn_mfma_f32_16x16x32_bf16(a, bv, acc[j], 0, 0, 0);
        }
    }
    __syncthreads();                          // xs reads done; reuse as vs

    short* vs = xs;                           // [32][71] bf16 v-tile bounce
#pragma unroll
    for (int j = 0; j < 6; j++) {
        const int col = (nh * 6 + j) * 16 + lo;
#pragma unroll
        for (int r = 0; r < 4; r++) {
            const int trow = rt * 16 + hi * 4 + r;
            float val = acc[j][r];
            if (col < 64)
                qws[(size_t)(row0 + trow) * HS + col] = f2bf(val * 0.125f);
            else if (col < 128)
                kws[(size_t)(row0 + trow) * HS + (col - 64)] = f2bf(val);
            else
                vs[trow * 71 + (col - 128)] = f2bf(val);
        }
    }
    __syncthreads();

    // coalesced write-out of v^T: [b][h][t]
    {
        const int h = tid >> 2, ts = tid & 3;
        short8 tmp;
#pragma unroll
        for (int e = 0; e < 8; e++) tmp[e] = vs[(ts * 8 + e) * 71 + h];
        *reinterpret_cast<short8*>(
            &vtg[((size_t)b * 64 + h) * T + t0 + ts * 8]) = tmp;
    }
}

// ---------------------------------------------------------------------------
// Kernel 2: causal flash attention, split-KV. Block = (b, qt, chunk).
// 4 waves x 16 q-rows; K/V^T double-buffered swizzled LDS, reg prefetch.
// Writes unnormalized partial (O', m, l) to ws.
// ---------------------------------------------------------------------------
__global__ __launch_bounds__(256) void attn(const short* __restrict__ qg,
                                            const short* __restrict__ kg,
                                            const short* __restrict__ vtg,
                                            float* __restrict__ part) {
    __shared__ short ks[2][64 * 64];
    __shared__ short vts[2][64 * 64];
    __shared__ short ps[4][16 * 64];

    const int tid  = threadIdx.x;
    const int lane = tid & 63, w = tid >> 6;
    const int lo   = lane & 15, hi = lane >> 4;
    const int bid  = blockIdx.x;
    const int b    = bid >> 6;
    const int qt   = 31 - ((bid >> 1) & 31);  // heaviest-first
    const int c    = bid & 1;
    const int nkt  = qt + 1, half = nkt >> 1;
    const int kt0   = c ? half : 0;
    const int niter = c ? (nkt - half) : half;
    float* pout = part + (size_t)((b * QT + qt) * SPLIT + c) * PSTRIDE;

    float m_[4], l_[4];
    f32x4 oacc[4];
#pragma unroll
    for (int r = 0; r < 4; r++) { m_[r] = -1e30f; l_[r] = 0.0f; }
#pragma unroll
    for (int i = 0; i < 4; i++) oacc[i] = f32x4{0.f, 0.f, 0.f, 0.f};

    if (niter > 0) {
        const int qrow = qt * 64 + w * 16 + lo;
        const size_t qbase = ((size_t)b * T + qrow) * HS;
        short8 qa0 = *reinterpret_cast<const short8*>(&qg[qbase + hi * 8]);
        short8 qa1 = *reinterpret_cast<const short8*>(&qg[qbase + 32 + hi * 8]);

        const int srow = tid >> 2, scs = tid & 3, r7 = srow & 7;
        const int w0 = srow * 64 + (((scs * 2)     ^ r7) << 3);
        const int w1 = srow * 64 + (((scs * 2 + 1) ^ r7) << 3);
        const size_t kgoff = (size_t)b * T * HS;
        const size_t vgoff = ((size_t)b * 64 + srow) * T;

        short8 ka, kb2, va, vb;
        {
            const short* kp = &kg[kgoff + (size_t)(kt0 * 64 + srow) * HS + scs * 16];
            ka = *reinterpret_cast<const short8*>(kp);
            kb2 = *reinterpret_cast<const short8*>(kp + 8);
            const short* vp = &vtg[vgoff + kt0 * 64 + scs * 16];
            va = *reinterpret_cast<const short8*>(vp);
            vb = *reinterpret_cast<const short8*>(vp + 8);
        }
        *reinterpret_cast<short8*>(&ks[0][w0])  = ka;
        *reinterpret_cast<short8*>(&ks[0][w1])  = kb2;
        *reinterpret_cast<short8*>(&vts[0][w0]) = va;
        *reinterpret_cast<short8*>(&vts[0][w1]) = vb;

        int cur = 0;
        for (int i = 0; i < niter; i++) {
            const int kt = kt0 + i;
            if (i + 1 < niter) {              // prefetch next tile -> regs
                const short* kp = &kg[kgoff + (size_t)((kt + 1) * 64 + srow) * HS + scs * 16];
                ka = *reinterpret_cast<const short8*>(kp);
                kb2 = *reinterpret_cast<const short8*>(kp + 8);
                const short* vp = &vtg[vgoff + (kt + 1) * 64 + scs * 16];
                va = *reinterpret_cast<const short8*>(vp);
                vb = *reinterpret_cast<const short8*>(vp + 8);
            }
            __syncthreads();                  // buf[cur] ready

            // ---- S = Q K^T ----
            f32x4 sacc[4];
#pragma unroll
            for (int nt = 0; nt < 4; nt++) sacc[nt] = f32x4{0.f, 0.f, 0.f, 0.f};
#pragma unroll
            for (int nt = 0; nt < 4; nt++) {
                const int row = nt * 16 + lo, rr = row & 7;
                short8 b0 = *reinterpret_cast<const short8*>(
                    &ks[cur][row * 64 + ((hi ^ rr) << 3)]);
                short8 b1 = *reinterpret_cast<const short8*>(
                    &ks[cur][row * 64 + (((hi + 4) ^ rr) << 3)]);
                sacc[nt] = __builtin_amdgcn_mfma_f32_16x16x32_bf16(qa0, b0, sacc[nt], 0, 0, 0);
                sacc[nt] = __builtin_amdgcn_mfma_f32_16x16x32_bf16(qa1, b1, sacc[nt], 0, 0, 0);
            }

            if (kt == qt) {                   // causal mask, diagonal tile
#pragma unroll
                for (int nt = 0; nt < 4; nt++)
#pragma unroll
                    for (int r = 0; r < 4; r++)
                        if (nt * 16 + lo > w * 16 + hi * 4 + r) sacc[nt][r] = -1e30f;
            }

            // ---- online softmax ----
#pragma unroll
            for (int r = 0; r < 4; r++) {
                float t0m = fmaxf(fmaxf(sacc[0][r], sacc[1][r]),
                                  fmaxf(sacc[2][r], sacc[3][r]));
#pragma unroll
                for (int off = 1; off < 16; off <<= 1) t0m = fmaxf(t0m, __shfl_xor(t0m, off));
                float mnew = fmaxf(m_[r], t0m);
                float corr = __expf(m_[r] - mnew);
                float psum = 0.0f;
#pragma unroll
                for (int nt = 0; nt < 4; nt++) {
                    float p = __expf(sacc[nt][r] - mnew);
                    sacc[nt][r] = p;
                    psum += p;
                }
#pragma unroll
                for (int off = 1; off < 16; off <<= 1) psum += __shfl_xor(psum, off);
                l_[r] = l_[r] * corr + psum;
                m_[r] = mnew;
#pragma unroll
                for (int nt = 0; nt < 4; nt++) oacc[nt][r] *= corr;
            }

            // ---- P -> LDS bf16 (wave-private, swizzled) ----
#pragma unroll
            for (int nt = 0; nt < 4; nt++)
#pragma unroll
                for (int r = 0; r < 4; r++) {
                    const int qr = hi * 4 + r;
                    const int seg = nt * 2 + (lo >> 3);
                    ps[w][qr * 64 + ((seg ^ (qr & 7)) << 3) + (lo & 7)] = f2bf(sacc[nt][r]);
                }

            // ---- O += P V ----
            const int pl7 = lo & 7;
            short8 pa0 = *reinterpret_cast<const short8*>(
                &ps[w][lo * 64 + ((hi ^ pl7) << 3)]);
            short8 pa1 = *reinterpret_cast<const short8*>(
                &ps[w][lo * 64 + (((hi + 4) ^ pl7) << 3)]);
#pragma unroll
            for (int nt = 0; nt < 4; nt++) {
                const int row = nt * 16 + lo, rr = row & 7;
                short8 b0 = *reinterpret_cast<const short8*>(
                    &vts[cur][row * 64 + ((hi ^ rr) << 3)]);
                short8 b1 = *reinterpret_cast<const short8*>(
                    &vts[cur][row * 64 + (((hi + 4) ^ rr) << 3)]);
                oacc[nt] = __builtin_amdgcn_mfma_f32_16x16x32_bf16(pa0, b0, oacc[nt], 0, 0, 0);
                oacc[nt] = __builtin_amdgcn_mfma_f32_16x16x32_bf16(pa1, b1, oacc[nt], 0, 0, 0);
            }

            if (i + 1 < niter) {              // write prefetched tile
                *reinterpret_cast<short8*>(&ks[cur ^ 1][w0])  = ka;
                *reinterpret_cast<short8*>(&ks[cur ^ 1][w1])  = kb2;
                *reinterpret_cast<short8*>(&vts[cur ^ 1][w0]) = va;
                *reinterpret_cast<short8*>(&vts[cur ^ 1][w1]) = vb;
            }
            cur ^= 1;
        }
    }

    // ---- write partial (unnormalized O', m, l) ----
#pragma unroll
    for (int nt = 0; nt < 4; nt++)
#pragma unroll
        for (int r = 0; r < 4; r++)
            pout[(w * 16 + hi * 4 + r) * 64 + nt * 16 + lo] = oacc[nt][r];
    if (lo == 0) {
#pragma unroll
        for (int r = 0; r < 4; r++) {
            const int row = w * 16 + hi * 4 + r;
            pout[4096 + row] = m_[r];
            pout[4160 + row] = l_[r];
        }
    }
}

// ---------------------------------------------------------------------------
// Kernel 3: combine the SPLIT partials -> normalized fp32 output.
// ---------------------------------------------------------------------------
__global__ __launch_bounds__(256) void combine(const float* __restrict__ part,
                                               float* __restrict__ out) {
    const int bid = blockIdx.x;               // b*32 + qt
    const int b = bid >> 5, qt = bid & 31;
    const float* p0 = part + (size_t)(bid * SPLIT) * PSTRIDE;
    const float* p1 = p0 + PSTRIDE;
    const int row = threadIdx.x >> 2, cs = threadIdx.x & 3;
    float m0 = p0[4096 + row], l0 = p0[4160 + row];
    float m1 = p1[4096 + row], l1 = p1[4160 + row];
    float M  = fmaxf(m0, m1);
    float a0 = __expf(m0 - M), a1 = __expf(m1 - M);
    float inv = 1.0f / (l0 * a0 + l1 * a1);
    const float* r0 = p0 + row * 64 + cs * 16;
    const float* r1 = p1 + row * 64 + cs * 16;
    float* o = out + ((size_t)b * T + qt * 64 + row) * HS + cs * 16;
#pragma unroll
    for (int i = 0; i < 4; i++) {
        float4 v0 = *reinterpret_cast<const float4*>(r0 + i * 4);
        float4 v1 = *reinterpret_cast<const float4*>(r1 + i * 4);
        float4 res;
        res.x = (v0.x * a0 + v1.x * a1) * inv;
        res.y = (v0.y * a0 + v1.y * a1) * inv;
        res.z = (v0.z * a0 + v1.z * a1) * inv;
        res.w = (v0.w * a0 + v1.w * a1) * inv;
        *reinterpret_cast<float4*>(o + i * 4) = res;
    }
}

// ---------------------------------------------------------------------------
extern "C" void kernel_launch(void* const* d_in, const int* in_sizes, int n_in,
                              void* d_out, int out_size, void* d_ws, size_t ws_size,
                              hipStream_t stream) {
    const float* x  = (const float*)d_in[0];
    const float* Wq = (const float*)d_in[1];
    const float* Wk = (const float*)d_in[2];
    const float* Wv = (const float*)d_in[3];
    float* out = (float*)d_out;

    short* ws   = (short*)d_ws;
    short* qws  = ws;
    short* kws  = qws + (size_t)BT * HS;
    short* vtws = kws + (size_t)BT * HS;
    short* Wt   = vtws + (size_t)BT * HS;
    float* part = (float*)(Wt + (size_t)192 * D);

    wt_kernel<<<192, 256, 0, stream>>>(Wq, Wk, Wv, Wt);
    qkv_proj<<<BT / 32, 256, 0, stream>>>(x, Wt, qws, kws, vtws);
    attn<<<Bb * QT * SPLIT, 256, 0, stream>>>(qws, kws, vtws, part);
    combine<<<Bb * QT, 256, 0, stream>>>(part, out);
}

// Round 7
// 64.312 us; speedup vs baseline: 1.7934x; 1.4009x over previous
//
#include <hip/hip_runtime.h>

typedef float  f32x4  __attribute__((ext_vector_type(4)));
typedef short  short8 __attribute__((ext_vector_type(8)));
typedef short  short4_ __attribute__((ext_vector_type(4)));

constexpr int Bb = 8, T = 2048, D = 768, HS = 64;
constexpr int BT = Bb * T;
constexpr int QT = T / 64;              // 32 q-tiles per batch
constexpr int PSTRIDE = 64 * 64 + 128;  // floats per partial (O' + m + l)

__device__ __forceinline__ short f2bf(float f) {
    unsigned u = __builtin_bit_cast(unsigned, f);
    unsigned r = (u + 0x7FFFu + ((u >> 16) & 1u)) >> 16;
    return (short)r;
}

__device__ __forceinline__ void gld_lds16(const short* g, short* l) {
    __builtin_amdgcn_global_load_lds(
        (const __attribute__((address_space(1))) unsigned int*)g,
        (__attribute__((address_space(3))) unsigned int*)l, 16, 0, 0);
}

// ---------------------------------------------------------------------------
// Kernel 0: transpose Wq|Wk|Wv (fp32 [768][64] each) -> Wt bf16 [192][768]
// ---------------------------------------------------------------------------
__global__ __launch_bounds__(256) void wt_kernel(const float* __restrict__ Wq,
                                                 const float* __restrict__ Wk,
                                                 const float* __restrict__ Wv,
                                                 short* __restrict__ Wt) {
    int n = blockIdx.x;                       // 0..191 composite output col
    const float* W = (n < 64) ? Wq : (n < 128) ? Wk : Wv;
    int c = n & 63;
    for (int kk = threadIdx.x; kk < D; kk += 256)
        Wt[n * D + kk] = f2bf(W[kk * HS + c]);
}

// ---------------------------------------------------------------------------
// Kernel 1: QKV projection GEMM. 512 blocks x 32 rows x 192 cols, 8 waves.
// W chunk: global_load_lds (linear [192][64]); x chunk: coalesced reg-stage
// fp32->bf16 into padded [32][72]. Double-buffered, 1 barrier/chunk.
// q pre-scaled 1/8; v written transposed [b][h][t].
// ---------------------------------------------------------------------------
__global__ __launch_bounds__(512) void qkv_proj(const float* __restrict__ x,
                                                const short* __restrict__ Wt,
                                                short* __restrict__ qws,
                                                short* __restrict__ kws,
                                                short* __restrict__ vtg) {
    __shared__ alignas(16) short xs[2][32 * 72];     // 9.2 KB
    __shared__ alignas(16) short wtile[2][192 * 64]; // 49.2 KB

    const int tid  = threadIdx.x;             // 0..511
    const int lane = tid & 63, w = tid >> 6;
    const int lo   = lane & 15, hi = lane >> 4;
    const int wr   = w >> 2, wc = w & 3;      // wave row (2) x col (4)
    const int row0 = blockIdx.x * 32;
    const int b    = row0 >> 11, t0 = row0 & 2047;

    const int sxr = tid >> 4, sxs = tid & 15; // x staging: row, float4 seg
    const float* xsrc = &x[(size_t)(row0 + sxr) * D + sxs * 4];

    f32x4 acc[3];
#pragma unroll
    for (int j = 0; j < 3; j++) acc[j] = f32x4{0.f, 0.f, 0.f, 0.f};

#define STAGE(bb, kc)                                                         \
    {                                                                         \
        _Pragma("unroll")                                                     \
        for (int it = 0; it < 3; it++) {                                      \
            int ci = it * 512 + w * 64 + lane;                                \
            int n = ci >> 3, seg = ci & 7;                                    \
            gld_lds16(&Wt[(size_t)n * D + (kc) * 64 + seg * 8],               \
                      &wtile[bb][(it * 512 + w * 64) * 8]);                   \
        }                                                                     \
        float4 f = *reinterpret_cast<const float4*>(xsrc + (kc) * 64);        \
        short4_ h;                                                            \
        h[0] = f2bf(f.x); h[1] = f2bf(f.y); h[2] = f2bf(f.z); h[3] = f2bf(f.w);\
        *reinterpret_cast<short4_*>(&xs[bb][sxr * 72 + sxs * 4]) = h;         \
    }

    STAGE(0, 0);
    __syncthreads();

    for (int kc = 0; kc < 12; kc++) {
        const int bb = kc & 1;
        if (kc + 1 < 12) STAGE(bb ^ 1, kc + 1);

        const int arow = (wr * 16 + lo) * 72;
        short8 a0 = *reinterpret_cast<const short8*>(&xs[bb][arow + hi * 8]);
        short8 a1 = *reinterpret_cast<const short8*>(&xs[bb][arow + 32 + hi * 8]);
#pragma unroll
        for (int j = 0; j < 3; j++) {
            const int c = (wc * 48 + j * 16 + lo) * 64;
            short8 b0 = *reinterpret_cast<const short8*>(&wtile[bb][c + hi * 8]);
            short8 b1 = *reinterpret_cast<const short8*>(&wtile[bb][c + 32 + hi * 8]);
            acc[j] = __builtin_amdgcn_mfma_f32_16x16x32_bf16(a0, b0, acc[j], 0, 0, 0);
            acc[j] = __builtin_amdgcn_mfma_f32_16x16x32_bf16(a1, b1, acc[j], 0, 0, 0);
        }
        __syncthreads();
    }
#undef STAGE

    // ---- epilogue ----
    const int orow = row0 + wr * 16 + hi * 4;
#pragma unroll
    for (int j = 0; j < 3; j++) {
        const int cb = wc * 48 + j * 16;      // wave-uniform frag col base
        if (cb < 64) {
#pragma unroll
            for (int r = 0; r < 4; r++)
                qws[(size_t)(orow + r) * HS + cb + lo] = f2bf(acc[j][r] * 0.125f);
        } else if (cb < 128) {
#pragma unroll
            for (int r = 0; r < 4; r++)
                kws[(size_t)(orow + r) * HS + cb - 64 + lo] = f2bf(acc[j][r]);
        } else {
            short4_ pv;
#pragma unroll
            for (int r = 0; r < 4; r++) pv[r] = f2bf(acc[j][r]);
            *reinterpret_cast<short4_*>(
                &vtg[((size_t)b * 64 + cb - 128 + lo) * T + t0 + wr * 16 + hi * 4]) = pv;
        }
    }
}

// ---------------------------------------------------------------------------
// Kernel 2: causal flash attention, split-KV (runtime S). Block=(b,qt,chunk).
// 4 waves x 16 q-rows; K/V^T double-buffered swizzled LDS, reg prefetch.
// ---------------------------------------------------------------------------
__global__ __launch_bounds__(256) void attn(const short* __restrict__ qg,
                                            const short* __restrict__ kg,
                                            const short* __restrict__ vtg,
                                            float* __restrict__ part, int S) {
    __shared__ short ks[2][64 * 64];
    __shared__ short vts[2][64 * 64];
    __shared__ short ps[4][16 * 64];

    const int tid  = threadIdx.x;
    const int lane = tid & 63, w = tid >> 6;
    const int lo   = lane & 15, hi = lane >> 4;
    const int bid  = blockIdx.x;
    const int per_b = QT * S;
    const int b    = bid / per_b;
    const int r2   = bid % per_b;
    const int qt   = 31 - (r2 / S);           // heaviest-first
    const int c    = r2 % S;
    const int nkt  = qt + 1;
    const int base = nkt / S, rem = nkt % S;
    const int niter = base + (c < rem ? 1 : 0);
    const int kt0   = c * base + (c < rem ? c : rem);
    float* pout = part + (size_t)((b * QT + qt) * S + c) * PSTRIDE;

    float m_[4], l_[4];
    f32x4 oacc[4];
#pragma unroll
    for (int r = 0; r < 4; r++) { m_[r] = -1e30f; l_[r] = 0.0f; }
#pragma unroll
    for (int i = 0; i < 4; i++) oacc[i] = f32x4{0.f, 0.f, 0.f, 0.f};

    if (niter > 0) {
        const int qrow = qt * 64 + w * 16 + lo;
        const size_t qbase = ((size_t)b * T + qrow) * HS;
        short8 qa0 = *reinterpret_cast<const short8*>(&qg[qbase + hi * 8]);
        short8 qa1 = *reinterpret_cast<const short8*>(&qg[qbase + 32 + hi * 8]);

        const int srow = tid >> 2, scs = tid & 3, r7 = srow & 7;
        const int w0 = srow * 64 + (((scs * 2)     ^ r7) << 3);
        const int w1 = srow * 64 + (((scs * 2 + 1) ^ r7) << 3);
        const size_t kgoff = (size_t)b * T * HS;
        const size_t vgoff = ((size_t)b * 64 + srow) * T;

        short8 ka, kb2, va, vb;
        {
            const short* kp = &kg[kgoff + (size_t)(kt0 * 64 + srow) * HS + scs * 16];
            ka = *reinterpret_cast<const short8*>(kp);
            kb2 = *reinterpret_cast<const short8*>(kp + 8);
            const short* vp = &vtg[vgoff + kt0 * 64 + scs * 16];
            va = *reinterpret_cast<const short8*>(vp);
            vb = *reinterpret_cast<const short8*>(vp + 8);
        }
        *reinterpret_cast<short8*>(&ks[0][w0])  = ka;
        *reinterpret_cast<short8*>(&ks[0][w1])  = kb2;
        *reinterpret_cast<short8*>(&vts[0][w0]) = va;
        *reinterpret_cast<short8*>(&vts[0][w1]) = vb;

        int cur = 0;
        for (int i = 0; i < niter; i++) {
            const int kt = kt0 + i;
            if (i + 1 < niter) {              // prefetch next tile -> regs
                const short* kp = &kg[kgoff + (size_t)((kt + 1) * 64 + srow) * HS + scs * 16];
                ka = *reinterpret_cast<const short8*>(kp);
                kb2 = *reinterpret_cast<const short8*>(kp + 8);
                const short* vp = &vtg[vgoff + (kt + 1) * 64 + scs * 16];
                va = *reinterpret_cast<const short8*>(vp);
                vb = *reinterpret_cast<const short8*>(vp + 8);
            }
            __syncthreads();                  // buf[cur] ready

            // ---- S = Q K^T ----
            f32x4 sacc[4];
#pragma unroll
            for (int nt = 0; nt < 4; nt++) sacc[nt] = f32x4{0.f, 0.f, 0.f, 0.f};
            __builtin_amdgcn_s_setprio(1);
#pragma unroll
            for (int nt = 0; nt < 4; nt++) {
                const int row = nt * 16 + lo, rr = row & 7;
                short8 b0 = *reinterpret_cast<const short8*>(
                    &ks[cur][row * 64 + ((hi ^ rr) << 3)]);
                short8 b1 = *reinterpret_cast<const short8*>(
                    &ks[cur][row * 64 + (((hi + 4) ^ rr) << 3)]);
                sacc[nt] = __builtin_amdgcn_mfma_f32_16x16x32_bf16(qa0, b0, sacc[nt], 0, 0, 0);
                sacc[nt] = __builtin_amdgcn_mfma_f32_16x16x32_bf16(qa1, b1, sacc[nt], 0, 0, 0);
            }
            __builtin_amdgcn_s_setprio(0);

            if (kt == qt) {                   // causal mask, diagonal tile
#pragma unroll
                for (int nt = 0; nt < 4; nt++)
#pragma unroll
                    for (int r = 0; r < 4; r++)
                        if (nt * 16 + lo > w * 16 + hi * 4 + r) sacc[nt][r] = -1e30f;
            }

            // ---- online softmax ----
#pragma unroll
            for (int r = 0; r < 4; r++) {
                float t0m = fmaxf(fmaxf(sacc[0][r], sacc[1][r]),
                                  fmaxf(sacc[2][r], sacc[3][r]));
#pragma unroll
                for (int off = 1; off < 16; off <<= 1) t0m = fmaxf(t0m, __shfl_xor(t0m, off));
                float mnew = fmaxf(m_[r], t0m);
                float corr = __expf(m_[r] - mnew);
                float psum = 0.0f;
#pragma unroll
                for (int nt = 0; nt < 4; nt++) {
                    float p = __expf(sacc[nt][r] - mnew);
                    sacc[nt][r] = p;
                    psum += p;
                }
#pragma unroll
                for (int off = 1; off < 16; off <<= 1) psum += __shfl_xor(psum, off);
                l_[r] = l_[r] * corr + psum;
                m_[r] = mnew;
#pragma unroll
                for (int nt = 0; nt < 4; nt++) oacc[nt][r] *= corr;
            }

            // ---- P -> LDS bf16 (wave-private, swizzled) ----
#pragma unroll
            for (int nt = 0; nt < 4; nt++)
#pragma unroll
                for (int r = 0; r < 4; r++) {
                    const int qr = hi * 4 + r;
                    const int seg = nt * 2 + (lo >> 3);
                    ps[w][qr * 64 + ((seg ^ (qr & 7)) << 3) + (lo & 7)] = f2bf(sacc[nt][r]);
                }

            // ---- O += P V ----
            const int pl7 = lo & 7;
            short8 pa0 = *reinterpret_cast<const short8*>(
                &ps[w][lo * 64 + ((hi ^ pl7) << 3)]);
            short8 pa1 = *reinterpret_cast<const short8*>(
                &ps[w][lo * 64 + (((hi + 4) ^ pl7) << 3)]);
            __builtin_amdgcn_s_setprio(1);
#pragma unroll
            for (int nt = 0; nt < 4; nt++) {
                const int row = nt * 16 + lo, rr = row & 7;
                short8 b0 = *reinterpret_cast<const short8*>(
                    &vts[cur][row * 64 + ((hi ^ rr) << 3)]);
                short8 b1 = *reinterpret_cast<const short8*>(
                    &vts[cur][row * 64 + (((hi + 4) ^ rr) << 3)]);
                oacc[nt] = __builtin_amdgcn_mfma_f32_16x16x32_bf16(pa0, b0, oacc[nt], 0, 0, 0);
                oacc[nt] = __builtin_amdgcn_mfma_f32_16x16x32_bf16(pa1, b1, oacc[nt], 0, 0, 0);
            }
            __builtin_amdgcn_s_setprio(0);

            if (i + 1 < niter) {              // write prefetched tile
                *reinterpret_cast<short8*>(&ks[cur ^ 1][w0])  = ka;
                *reinterpret_cast<short8*>(&ks[cur ^ 1][w1])  = kb2;
                *reinterpret_cast<short8*>(&vts[cur ^ 1][w0]) = va;
                *reinterpret_cast<short8*>(&vts[cur ^ 1][w1]) = vb;
            }
            cur ^= 1;
        }
    }

    // ---- write partial (unnormalized O', m, l) ----
#pragma unroll
    for (int nt = 0; nt < 4; nt++)
#pragma unroll
        for (int r = 0; r < 4; r++)
            pout[(w * 16 + hi * 4 + r) * 64 + nt * 16 + lo] = oacc[nt][r];
    if (lo == 0) {
#pragma unroll
        for (int r = 0; r < 4; r++) {
            const int row = w * 16 + hi * 4 + r;
            pout[4096 + row] = m_[r];
            pout[4160 + row] = l_[r];
        }
    }
}

// ---------------------------------------------------------------------------
// Kernel 3: combine the S partials -> normalized fp32 output.
// ---------------------------------------------------------------------------
__global__ __launch_bounds__(256) void combine(const float* __restrict__ part,
                                               float* __restrict__ out, int S) {
    const int bid = blockIdx.x;               // b*32 + qt
    const int b = bid >> 5, qt = bid & 31;
    const float* p = part + (size_t)bid * S * PSTRIDE;
    const int row = threadIdx.x >> 2, cs = threadIdx.x & 3;

    float mv[4], lv[4], av[4];
    float M = -1e30f;
    for (int s = 0; s < S; s++) {
        mv[s] = p[(size_t)s * PSTRIDE + 4096 + row];
        lv[s] = p[(size_t)s * PSTRIDE + 4160 + row];
        M = fmaxf(M, mv[s]);
    }
    float den = 0.0f;
    for (int s = 0; s < S; s++) { av[s] = __expf(mv[s] - M); den += lv[s] * av[s]; }
    float inv = 1.0f / den;

    float* o = out + ((size_t)b * T + qt * 64 + row) * HS + cs * 16;
#pragma unroll
    for (int i = 0; i < 4; i++) {
        float4 res = make_float4(0.f, 0.f, 0.f, 0.f);
        for (int s = 0; s < S; s++) {
            float4 v = *reinterpret_cast<const float4*>(
                p + (size_t)s * PSTRIDE + row * 64 + cs * 16 + i * 4);
            res.x += v.x * av[s]; res.y += v.y * av[s];
            res.z += v.z * av[s]; res.w += v.w * av[s];
        }
        res.x *= inv; res.y *= inv; res.z *= inv; res.w *= inv;
        *reinterpret_cast<float4*>(o + i * 4) = res;
    }
}

// ---------------------------------------------------------------------------
extern "C" void kernel_launch(void* const* d_in, const int* in_sizes, int n_in,
                              void* d_out, int out_size, void* d_ws, size_t ws_size,
                              hipStream_t stream) {
    const float* x  = (const float*)d_in[0];
    const float* Wq = (const float*)d_in[1];
    const float* Wk = (const float*)d_in[2];
    const float* Wv = (const float*)d_in[3];
    float* out = (float*)d_out;

    short* ws   = (short*)d_ws;
    short* qws  = ws;
    short* kws  = qws + (size_t)BT * HS;
    short* vtws = kws + (size_t)BT * HS;
    short* Wt   = vtws + (size_t)BT * HS;
    float* part = (float*)(Wt + (size_t)192 * D);

    const size_t fixed = (size_t)3 * BT * HS * 2 + (size_t)192 * D * 2;
    int S = 4;
    while (S > 1 && fixed + (size_t)Bb * QT * S * PSTRIDE * 4 > ws_size) S >>= 1;

    wt_kernel<<<192, 256, 0, stream>>>(Wq, Wk, Wv, Wt);
    qkv_proj<<<BT / 32, 512, 0, stream>>>(x, Wt, qws, kws, vtws);
    attn<<<Bb * QT * S, 256, 0, stream>>>(qws, kws, vtws, part, S);
    combine<<<Bb * QT, 256, 0, stream>>>(part, out, S);
}

// Round 9
// 63.417 us; speedup vs baseline: 1.8188x; 1.0141x over previous
//
#include <hip/hip_runtime.h>

typedef float  f32x4  __attribute__((ext_vector_type(4)));
typedef short  short8 __attribute__((ext_vector_type(8)));
typedef short  short4_ __attribute__((ext_vector_type(4)));

constexpr int Bb = 8, T = 2048, D = 768, HS = 64;
constexpr int BT = Bb * T;
constexpr int QT = T / 64;              // 32 q-tiles per batch
constexpr int PSTRIDE = 64 * 64 + 128;  // floats per partial (O' + m + l)

__device__ __forceinline__ short f2bf(float f) {
    unsigned u = __builtin_bit_cast(unsigned, f);
    unsigned r = (u + 0x7FFFu + ((u >> 16) & 1u)) >> 16;
    return (short)r;
}

__device__ __forceinline__ void gld_lds16(const short* g, short* l) {
    __builtin_amdgcn_global_load_lds(
        (const __attribute__((address_space(1))) unsigned int*)g,
        (__attribute__((address_space(3))) unsigned int*)l, 16, 0, 0);
}

// ---------------------------------------------------------------------------
// Kernel 0: transpose Wq|Wk|Wv (fp32 [768][64] each) -> Wt bf16 [192][768]
// ---------------------------------------------------------------------------
__global__ __launch_bounds__(256) void wt_kernel(const float* __restrict__ Wq,
                                                 const float* __restrict__ Wk,
                                                 const float* __restrict__ Wv,
                                                 short* __restrict__ Wt) {
    int n = blockIdx.x;                       // 0..191 composite output col
    const float* W = (n < 64) ? Wq : (n < 128) ? Wk : Wv;
    int c = n & 63;
    for (int kk = threadIdx.x; kk < D; kk += 256)
        Wt[n * D + kk] = f2bf(W[kk * HS + c]);
}

// ---------------------------------------------------------------------------
// Kernel 1: QKV projection GEMM. 256 blocks x 64 rows x 192 cols, 8 waves.
// W chunk: global_load_lds with PRE-SWIZZLED global source (rule #21) so the
// linear LDS tile is XOR-swizzled; MFMA B-reads XOR the granule by (row&7)
// -> 16-way bank conflict becomes 2-way. x chunk: coalesced reg-stage
// fp32->bf16 into padded [64][72]. Double-buffered, 1 barrier/chunk.
// q pre-scaled 1/8; v written transposed [b][h][t].
// ---------------------------------------------------------------------------
__global__ __launch_bounds__(512) void qkv_proj(const float* __restrict__ x,
                                                const short* __restrict__ Wt,
                                                short* __restrict__ qws,
                                                short* __restrict__ kws,
                                                short* __restrict__ vtg) {
    __shared__ alignas(16) short xs[2][64 * 72];     // 18.4 KB
    __shared__ alignas(16) short wtile[2][192 * 64]; // 49.2 KB

    const int tid  = threadIdx.x;             // 0..511
    const int lane = tid & 63, w = tid >> 6;
    const int lo   = lane & 15, hi = lane >> 4;
    const int wr   = w >> 2, wc = w & 3;      // wave row (2) x col (4)
    const int row0 = blockIdx.x * 64;
    const int b    = row0 >> 11, t0 = row0 & 2047;

    const int xr0 = tid >> 4, xsg = tid & 15; // x staging: row(0..31), f4 seg
    const float* xsrc0 = &x[(size_t)(row0 + xr0) * D + xsg * 4];
    const float* xsrc1 = &x[(size_t)(row0 + 32 + xr0) * D + xsg * 4];

    f32x4 acc[6];
#pragma unroll
    for (int j = 0; j < 6; j++) acc[j] = f32x4{0.f, 0.f, 0.f, 0.f};

#define STAGE(bb, kc)                                                          \
    {                                                                          \
        _Pragma("unroll")                                                      \
        for (int it = 0; it < 3; it++) {                                       \
            int ci = it * 512 + w * 64 + lane;                                 \
            int n = ci >> 3, seg = ci & 7;                                     \
            gld_lds16(&Wt[(size_t)n * D + (kc) * 64 + ((seg ^ (n & 7)) << 3)], \
                      &wtile[bb][(it * 512 + w * 64) * 8]);                    \
        }                                                                      \
        float4 f0 = *reinterpret_cast<const float4*>(xsrc0 + (kc) * 64);       \
        float4 f1 = *reinterpret_cast<const float4*>(xsrc1 + (kc) * 64);       \
        short4_ h0, h1;                                                        \
        h0[0] = f2bf(f0.x); h0[1] = f2bf(f0.y); h0[2] = f2bf(f0.z); h0[3] = f2bf(f0.w); \
        h1[0] = f2bf(f1.x); h1[1] = f2bf(f1.y); h1[2] = f2bf(f1.z); h1[3] = f2bf(f1.w); \
        *reinterpret_cast<short4_*>(&xs[bb][xr0 * 72 + xsg * 4]) = h0;         \
        *reinterpret_cast<short4_*>(&xs[bb][(32 + xr0) * 72 + xsg * 4]) = h1;  \
    }

    STAGE(0, 0);
    __syncthreads();

    for (int kc = 0; kc < 12; kc++) {
        const int bb = kc & 1;
        if (kc + 1 < 12) STAGE(bb ^ 1, kc + 1);

#pragma unroll
        for (int m = 0; m < 2; m++) {
            const int ar = (wr * 32 + m * 16 + lo) * 72;
            short8 a0 = *reinterpret_cast<const short8*>(&xs[bb][ar + hi * 8]);
            short8 a1 = *reinterpret_cast<const short8*>(&xs[bb][ar + 32 + hi * 8]);
#pragma unroll
            for (int j = 0; j < 3; j++) {
                const int row = wc * 48 + j * 16 + lo;
                const int rx  = (row & 7) << 3;
                short8 b0 = *reinterpret_cast<const short8*>(
                    &wtile[bb][row * 64 + ((hi << 3) ^ rx)]);
                short8 b1 = *reinterpret_cast<const short8*>(
                    &wtile[bb][row * 64 + (((hi + 4) << 3) ^ rx)]);
                acc[m * 3 + j] = __builtin_amdgcn_mfma_f32_16x16x32_bf16(a0, b0, acc[m * 3 + j], 0, 0, 0);
                acc[m * 3 + j] = __builtin_amdgcn_mfma_f32_16x16x32_bf16(a1, b1, acc[m * 3 + j], 0, 0, 0);
            }
        }
        __syncthreads();
    }
#undef STAGE

    // ---- epilogue ----
#pragma unroll
    for (int m = 0; m < 2; m++) {
        const int orow = row0 + wr * 32 + m * 16 + hi * 4;
#pragma unroll
        for (int j = 0; j < 3; j++) {
            const int cb = wc * 48 + j * 16;  // wave-uniform frag col base
            const f32x4 a = acc[m * 3 + j];
            if (cb < 64) {
#pragma unroll
                for (int r = 0; r < 4; r++)
                    qws[(size_t)(orow + r) * HS + cb + lo] = f2bf(a[r] * 0.125f);
            } else if (cb < 128) {
#pragma unroll
                for (int r = 0; r < 4; r++)
                    kws[(size_t)(orow + r) * HS + cb - 64 + lo] = f2bf(a[r]);
            } else {
                short4_ pv;
#pragma unroll
                for (int r = 0; r < 4; r++) pv[r] = f2bf(a[r]);
                *reinterpret_cast<short4_*>(
                    &vtg[((size_t)b * 64 + cb - 128 + lo) * T + t0 + wr * 32 + m * 16 + hi * 4]) = pv;
            }
        }
    }
}

// ---------------------------------------------------------------------------
// Kernel 2: causal flash attention, split-KV (runtime S). Block=(b,qt,chunk).
// 4 waves x 16 q-rows; K/V^T double-buffered swizzled LDS, reg prefetch.
// ---------------------------------------------------------------------------
__global__ __launch_bounds__(256) void attn(const short* __restrict__ qg,
                                            const short* __restrict__ kg,
                                            const short* __restrict__ vtg,
                                            float* __restrict__ part, int S) {
    __shared__ short ks[2][64 * 64];
    __shared__ short vts[2][64 * 64];
    __shared__ short ps[4][16 * 64];

    const int tid  = threadIdx.x;
    const int lane = tid & 63, w = tid >> 6;
    const int lo   = lane & 15, hi = lane >> 4;
    const int bid  = blockIdx.x;
    const int per_b = QT * S;
    const int b    = bid / per_b;
    const int r2   = bid % per_b;
    const int qt   = 31 - (r2 / S);           // heaviest-first
    const int c    = r2 % S;
    const int nkt  = qt + 1;
    const int base = nkt / S, rem = nkt % S;
    const int niter = base + (c < rem ? 1 : 0);
    const int kt0   = c * base + (c < rem ? c : rem);
    float* pout = part + (size_t)((b * QT + qt) * S + c) * PSTRIDE;

    float m_[4], l_[4];
    f32x4 oacc[4];
#pragma unroll
    for (int r = 0; r < 4; r++) { m_[r] = -1e30f; l_[r] = 0.0f; }
#pragma unroll
    for (int i = 0; i < 4; i++) oacc[i] = f32x4{0.f, 0.f, 0.f, 0.f};

    if (niter > 0) {
        const int qrow = qt * 64 + w * 16 + lo;
        const size_t qbase = ((size_t)b * T + qrow) * HS;
        short8 qa0 = *reinterpret_cast<const short8*>(&qg[qbase + hi * 8]);
        short8 qa1 = *reinterpret_cast<const short8*>(&qg[qbase + 32 + hi * 8]);

        const int srow = tid >> 2, scs = tid & 3, r7 = srow & 7;
        const int w0 = srow * 64 + (((scs * 2)     ^ r7) << 3);
        const int w1 = srow * 64 + (((scs * 2 + 1) ^ r7) << 3);
        const size_t kgoff = (size_t)b * T * HS;
        const size_t vgoff = ((size_t)b * 64 + srow) * T;

        short8 ka, kb2, va, vb;
        {
            const short* kp = &kg[kgoff + (size_t)(kt0 * 64 + srow) * HS + scs * 16];
            ka = *reinterpret_cast<const short8*>(kp);
            kb2 = *reinterpret_cast<const short8*>(kp + 8);
            const short* vp = &vtg[vgoff + kt0 * 64 + scs * 16];
            va = *reinterpret_cast<const short8*>(vp);
            vb = *reinterpret_cast<const short8*>(vp + 8);
        }
        *reinterpret_cast<short8*>(&ks[0][w0])  = ka;
        *reinterpret_cast<short8*>(&ks[0][w1])  = kb2;
        *reinterpret_cast<short8*>(&vts[0][w0]) = va;
        *reinterpret_cast<short8*>(&vts[0][w1]) = vb;

        int cur = 0;
        for (int i = 0; i < niter; i++) {
            const int kt = kt0 + i;
            if (i + 1 < niter) {              // prefetch next tile -> regs
                const short* kp = &kg[kgoff + (size_t)((kt + 1) * 64 + srow) * HS + scs * 16];
                ka = *reinterpret_cast<const short8*>(kp);
                kb2 = *reinterpret_cast<const short8*>(kp + 8);
                const short* vp = &vtg[vgoff + (kt + 1) * 64 + scs * 16];
                va = *reinterpret_cast<const short8*>(vp);
                vb = *reinterpret_cast<const short8*>(vp + 8);
            }
            __syncthreads();                  // buf[cur] ready

            // ---- S = Q K^T ----
            f32x4 sacc[4];
#pragma unroll
            for (int nt = 0; nt < 4; nt++) sacc[nt] = f32x4{0.f, 0.f, 0.f, 0.f};
            __builtin_amdgcn_s_setprio(1);
#pragma unroll
            for (int nt = 0; nt < 4; nt++) {
                const int row = nt * 16 + lo, rr = row & 7;
                short8 b0 = *reinterpret_cast<const short8*>(
                    &ks[cur][row * 64 + ((hi ^ rr) << 3)]);
                short8 b1 = *reinterpret_cast<const short8*>(
                    &ks[cur][row * 64 + (((hi + 4) ^ rr) << 3)]);
                sacc[nt] = __builtin_amdgcn_mfma_f32_16x16x32_bf16(qa0, b0, sacc[nt], 0, 0, 0);
                sacc[nt] = __builtin_amdgcn_mfma_f32_16x16x32_bf16(qa1, b1, sacc[nt], 0, 0, 0);
            }
            __builtin_amdgcn_s_setprio(0);

            if (kt == qt) {                   // causal mask, diagonal tile
#pragma unroll
                for (int nt = 0; nt < 4; nt++)
#pragma unroll
                    for (int r = 0; r < 4; r++)
                        if (nt * 16 + lo > w * 16 + hi * 4 + r) sacc[nt][r] = -1e30f;
            }

            // ---- online softmax ----
#pragma unroll
            for (int r = 0; r < 4; r++) {
                float t0m = fmaxf(fmaxf(sacc[0][r], sacc[1][r]),
                                  fmaxf(sacc[2][r], sacc[3][r]));
#pragma unroll
                for (int off = 1; off < 16; off <<= 1) t0m = fmaxf(t0m, __shfl_xor(t0m, off));
                float mnew = fmaxf(m_[r], t0m);
                float corr = __expf(m_[r] - mnew);
                float psum = 0.0f;
#pragma unroll
                for (int nt = 0; nt < 4; nt++) {
                    float p = __expf(sacc[nt][r] - mnew);
                    sacc[nt][r] = p;
                    psum += p;
                }
#pragma unroll
                for (int off = 1; off < 16; off <<= 1) psum += __shfl_xor(psum, off);
                l_[r] = l_[r] * corr + psum;
                m_[r] = mnew;
#pragma unroll
                for (int nt = 0; nt < 4; nt++) oacc[nt][r] *= corr;
            }

            // ---- P -> LDS bf16 (wave-private, swizzled) ----
#pragma unroll
            for (int nt = 0; nt < 4; nt++)
#pragma unroll
                for (int r = 0; r < 4; r++) {
                    const int qr = hi * 4 + r;
                    const int seg = nt * 2 + (lo >> 3);
                    ps[w][qr * 64 + ((seg ^ (qr & 7)) << 3) + (lo & 7)] = f2bf(sacc[nt][r]);
                }

            // ---- O += P V ----
            const int pl7 = lo & 7;
            short8 pa0 = *reinterpret_cast<const short8*>(
                &ps[w][lo * 64 + ((hi ^ pl7) << 3)]);
            short8 pa1 = *reinterpret_cast<const short8*>(
                &ps[w][lo * 64 + (((hi + 4) ^ pl7) << 3)]);
            __builtin_amdgcn_s_setprio(1);
#pragma unroll
            for (int nt = 0; nt < 4; nt++) {
                const int row = nt * 16 + lo, rr = row & 7;
                short8 b0 = *reinterpret_cast<const short8*>(
                    &vts[cur][row * 64 + ((hi ^ rr) << 3)]);
                short8 b1 = *reinterpret_cast<const short8*>(
                    &vts[cur][row * 64 + (((hi + 4) ^ rr) << 3)]);
                oacc[nt] = __builtin_amdgcn_mfma_f32_16x16x32_bf16(pa0, b0, oacc[nt], 0, 0, 0);
                oacc[nt] = __builtin_amdgcn_mfma_f32_16x16x32_bf16(pa1, b1, oacc[nt], 0, 0, 0);
            }
            __builtin_amdgcn_s_setprio(0);

            if (i + 1 < niter) {              // write prefetched tile
                *reinterpret_cast<short8*>(&ks[cur ^ 1][w0])  = ka;
                *reinterpret_cast<short8*>(&ks[cur ^ 1][w1])  = kb2;
                *reinterpret_cast<short8*>(&vts[cur ^ 1][w0]) = va;
                *reinterpret_cast<short8*>(&vts[cur ^ 1][w1]) = vb;
            }
            cur ^= 1;
        }
    }

    // ---- write partial (unnormalized O', m, l) ----
#pragma unroll
    for (int nt = 0; nt < 4; nt++)
#pragma unroll
        for (int r = 0; r < 4; r++)
            pout[(w * 16 + hi * 4 + r) * 64 + nt * 16 + lo] = oacc[nt][r];
    if (lo == 0) {
#pragma unroll
        for (int r = 0; r < 4; r++) {
            const int row = w * 16 + hi * 4 + r;
            pout[4096 + row] = m_[r];
            pout[4160 + row] = l_[r];
        }
    }
}

// ---------------------------------------------------------------------------
// Kernel 3: combine the S partials -> normalized fp32 output.
// ---------------------------------------------------------------------------
__global__ __launch_bounds__(256) void combine(const float* __restrict__ part,
                                               float* __restrict__ out, int S) {
    const int bid = blockIdx.x;               // b*32 + qt
    const int b = bid >> 5, qt = bid & 31;
    const float* p = part + (size_t)bid * S * PSTRIDE;
    const int row = threadIdx.x >> 2, cs = threadIdx.x & 3;

    float mv[4], lv[4], av[4];
    float M = -1e30f;
    for (int s = 0; s < S; s++) {
        mv[s] = p[(size_t)s * PSTRIDE + 4096 + row];
        lv[s] = p[(size_t)s * PSTRIDE + 4160 + row];
        M = fmaxf(M, mv[s]);
    }
    float den = 0.0f;
    for (int s = 0; s < S; s++) { av[s] = __expf(mv[s] - M); den += lv[s] * av[s]; }
    float inv = 1.0f / den;

    float* o = out + ((size_t)b * T + qt * 64 + row) * HS + cs * 16;
#pragma unroll
    for (int i = 0; i < 4; i++) {
        float4 res = make_float4(0.f, 0.f, 0.f, 0.f);
        for (int s = 0; s < S; s++) {
            float4 v = *reinterpret_cast<const float4*>(
                p + (size_t)s * PSTRIDE + row * 64 + cs * 16 + i * 4);
            res.x += v.x * av[s]; res.y += v.y * av[s];
            res.z += v.z * av[s]; res.w += v.w * av[s];
        }
        res.x *= inv; res.y *= inv; res.z *= inv; res.w *= inv;
        *reinterpret_cast<float4*>(o + i * 4) = res;
    }
}

// ---------------------------------------------------------------------------
extern "C" void kernel_launch(void* const* d_in, const int* in_sizes, int n_in,
                              void* d_out, int out_size, void* d_ws, size_t ws_size,
                              hipStream_t stream) {
    const float* x  = (const float*)d_in[0];
    const float* Wq = (const float*)d_in[1];
    const float* Wk = (const float*)d_in[2];
    const float* Wv = (const float*)d_in[3];
    float* out = (float*)d_out;

    short* ws   = (short*)d_ws;
    short* qws  = ws;
    short* kws  = qws + (size_t)BT * HS;
    short* vtws = kws + (size_t)BT * HS;
    short* Wt   = vtws + (size_t)BT * HS;
    float* part = (float*)(Wt + (size_t)192 * D);

    const size_t fixed = (size_t)3 * BT * HS * 2 + (size_t)192 * D * 2;
    int S = 4;
    while (S > 1 && fixed + (size_t)Bb * QT * S * PSTRIDE * 4 > ws_size) S >>= 1;

    wt_kernel<<<192, 256, 0, stream>>>(Wq, Wk, Wv, Wt);
    qkv_proj<<<BT / 64, 512, 0, stream>>>(x, Wt, qws, kws, vtws);
    attn<<<Bb * QT * S, 256, 0, stream>>>(qws, kws, vtws, part, S);
    combine<<<Bb * QT, 256, 0, stream>>>(part, out, S);
}